// Round 4
// baseline (318.621 us; speedup 1.0000x reference)
//
#include <hip/hip_runtime.h>

// Problem constants (fixed by the reference):
//   B=4096, L=200, EMBEDDING_DIM=100, C=2 chunks of M=50, VOCAB=100000
constexpr int C_ = 2;
constexpr int M_ = 50;
constexpr int ED = 100;
constexpr float EPS = 1e-8f;

// tbl layout per row: (a0, a0*dw0, a1, a1*dw1)

// Anti-poison slot encoding: slot i holds (lo = h(i), hi = ~lo). The harness
// poison fill writes a repeating byte pattern, so lo == hi for poison, and
// hi == ~lo is unsatisfiable -> a slot can never LOOK valid before we write it.
// (Depends on the harness re-poisoning the workspace each iteration, which the
// R1/R2 profiles show: 268 MB fillBufferAligned dispatches every iteration.)
__device__ __forceinline__ unsigned long long slot_val(unsigned i) {
    const unsigned lo = (i + 1u) * 2654435761u;
    return ((unsigned long long)(~lo) << 32) | (unsigned long long)lo;
}

// ---------------------------------------------------------------------------
// Fused kernel: phase A = per-vocab-row stats (4 lanes per row, full-line
// loads), software grid barrier (all 1024 blocks co-resident at 4 blocks/CU,
// guaranteed by __launch_bounds__(256,4) -> VGPR<=128 -> capacity >= 4/CU),
// phase B = per-wave batch-element gather-reduce. One dispatch instead of
// two: removes one kernel-node submit + full inter-kernel drain.
// ---------------------------------------------------------------------------
__global__ __launch_bounds__(256, 4) void fused_kernel(
    const int*   __restrict__ idx,   // [B, L]
    const float* __restrict__ emb,   // [VOCAB, 100]
    const float* __restrict__ wgt,   // [100]
    const float* __restrict__ att,   // [100] = [2,50]
    float*       __restrict__ out,   // [B]
    float*       __restrict__ tbl,   // ws: [VOCAB * 4]
    unsigned long long* __restrict__ slots, // ws: [nblk + 1], last = GO
    int B, int L, int vocab, int nblk)
{
    __shared__ float2 s_uw[ED];   // (attend_u[e], weights[e])
    __shared__ float  s_su[C_];   // 1 / max(||u_c||, eps)

    const int t = threadIdx.x;
    if (t < ED) s_uw[t] = make_float2(att[t], wgt[t]);
    __syncthreads();
    if (t < C_) {
        float ss = 0.f;
        #pragma unroll
        for (int m = 0; m < M_; ++m) { float v = s_uw[t * M_ + m].x; ss += v * v; }
        s_su[t] = 1.0f / fmaxf(sqrtf(ss), EPS);
    }
    __syncthreads();

    const int wv   = t >> 6;
    const int lane = t & 63;
    const int g    = lane >> 2;               // row-in-wave (0..15)
    const int j    = lane & 3;                // float4 slot within group

    // ---------------- phase A: row stats, grid-stride over 16-row groups ----
    const int ngroups = (vocab + 15) >> 4;
    const int NW      = nblk * 4;             // total waves
    for (int task = blockIdx.x * 4 + wv; task < ngroups; task += NW) {
        const int r = task * 16 + g;          // uniform across the quad (j)
        if (r < vocab) {
            const float4* rowp = reinterpret_cast<const float4*>(emb + (long long)r * ED);

            float sq0 = 0.f, du0 = 0.f, dw0 = 0.f;
            float sq1 = 0.f, du1 = 0.f, dw1 = 0.f;

            #pragma unroll
            for (int it = 0; it < 6; ++it) {
                const float4 v = rowp[4 * it + j];   // 4 lanes -> one full 64B line
                const float xs[4] = { v.x, v.y, v.z, v.w };
                #pragma unroll
                for (int k = 0; k < 4; ++k) {
                    const int ebase = 16 * it + k;   // element e = ebase + 4*j
                    const float x   = xs[k];
                    const float2 uw = s_uw[ebase + 4 * j];
                    if (ebase + 12 < M_) {           // chunk 0 for every j
                        sq0 = fmaf(x, x, sq0); du0 = fmaf(x, uw.x, du0); dw0 = fmaf(x, uw.y, dw0);
                    } else if (ebase >= M_) {        // chunk 1 for every j
                        sq1 = fmaf(x, x, sq1); du1 = fmaf(x, uw.x, du1); dw1 = fmaf(x, uw.y, dw1);
                    } else {                         // straddle: j==0 chunk0, else chunk1
                        if (j == 0) { sq0 = fmaf(x, x, sq0); du0 = fmaf(x, uw.x, du0); dw0 = fmaf(x, uw.y, dw0); }
                        else        { sq1 = fmaf(x, x, sq1); du1 = fmaf(x, uw.x, du1); dw1 = fmaf(x, uw.y, dw1); }
                    }
                }
            }
            if (j == 0) {                     // tail float4 #24: elements 96..99
                const float4 v = rowp[24];
                const float xs[4] = { v.x, v.y, v.z, v.w };
                #pragma unroll
                for (int k = 0; k < 4; ++k) {
                    const float2 uw = s_uw[96 + k];
                    sq1 = fmaf(xs[k], xs[k], sq1); du1 = fmaf(xs[k], uw.x, du1); dw1 = fmaf(xs[k], uw.y, dw1);
                }
            }

            #pragma unroll
            for (int m = 1; m < 4; m <<= 1) { // quad reduce (whole quad active)
                sq0 += __shfl_xor(sq0, m, 4); du0 += __shfl_xor(du0, m, 4); dw0 += __shfl_xor(dw0, m, 4);
                sq1 += __shfl_xor(sq1, m, 4); du1 += __shfl_xor(du1, m, 4); dw1 += __shfl_xor(dw1, m, 4);
            }

            if (j == 0) {
                const float cos0 = du0 / fmaxf(sqrtf(sq0), EPS) * s_su[0];
                const float cos1 = du1 / fmaxf(sqrtf(sq1), EPS) * s_su[1];
                const float a0 = __expf(cos0);
                const float a1 = __expf(cos1);
                reinterpret_cast<float4*>(tbl)[r] = make_float4(a0, a0 * dw0, a1, a1 * dw1);
            }
        }
    }

    // ------- prefetch phase-B indices into registers (independent of tbl) ---
    const int  b      = blockIdx.x * 4 + wv;  // one wave per batch element
    const bool bvalid = (b < B);
    const int* ib     = idx + (long long)b * L;
    int pre[4];
    #pragma unroll
    for (int m = 0; m < 4; ++m) {
        const int l = lane + 64 * m;
        pre[m] = (bvalid && l < L) ? ib[l] : 0;
    }

    // ---------------- software grid barrier --------------------------------
    __threadfence();                          // push tbl writes toward LLC
    __syncthreads();                          // whole block done with phase A
    if (t == 0) {
        __hip_atomic_store(&slots[blockIdx.x], slot_val(blockIdx.x),
                           __ATOMIC_RELEASE, __HIP_MEMORY_SCOPE_AGENT);
    }
    if (blockIdx.x == 0) {                    // leader: scan all slots
        for (int s = t; s < nblk; s += 256) {
            const unsigned long long want = slot_val((unsigned)s);
            while (__hip_atomic_load(&slots[s], __ATOMIC_ACQUIRE,
                                     __HIP_MEMORY_SCOPE_AGENT) != want)
                __builtin_amdgcn_s_sleep(8);
        }
        __syncthreads();
        if (t == 0) {
            __threadfence();
            __hip_atomic_store(&slots[nblk], slot_val(0x40000000u),
                               __ATOMIC_RELEASE, __HIP_MEMORY_SCOPE_AGENT);
        }
    }
    if (t == 0) {                             // everyone waits on GO
        const unsigned long long wantgo = slot_val(0x40000000u);
        while (__hip_atomic_load(&slots[nblk], __ATOMIC_ACQUIRE,
                                 __HIP_MEMORY_SCOPE_AGENT) != wantgo)
            __builtin_amdgcn_s_sleep(32);
    }
    __syncthreads();
    __threadfence();                          // invalidate stale caches

    // ---------------- phase B: gather-reduce per batch element --------------
    if (bvalid) {
        float a0 = 0.f, ap0 = 0.f, a1 = 0.f, ap1 = 0.f;
        const float4* tb4 = reinterpret_cast<const float4*>(tbl);
        #pragma unroll
        for (int m = 0; m < 4; ++m) {
            const int l = lane + 64 * m;
            if (l < L) {
                const float4 v = tb4[pre[m]];
                a0 += v.x; ap0 += v.y; a1 += v.z; ap1 += v.w;
            }
        }
        for (int l = lane + 256; l < L; l += 64) {  // generic L fallback
            const float4 v = tb4[ib[l]];
            a0 += v.x; ap0 += v.y; a1 += v.z; ap1 += v.w;
        }
        #pragma unroll
        for (int off = 32; off > 0; off >>= 1) {
            a0  += __shfl_down(a0,  off, 64);
            a1  += __shfl_down(a1,  off, 64);
            ap0 += __shfl_down(ap0, off, 64);
            ap1 += __shfl_down(ap1, off, 64);
        }
        if (lane == 0) out[b] = ap0 / a0 + ap1 / a1;
    }
}

// ---------------------------------------------------------------------------
// Fallback two-kernel path (harness-verified R2 structure), used only if the
// grid would be too large for guaranteed co-residency.
// ---------------------------------------------------------------------------
__global__ __launch_bounds__(256) void row_stats_kernel(
    const float* __restrict__ emb, const float* __restrict__ wgt,
    const float* __restrict__ att, float* __restrict__ tbl, int vocab)
{
    __shared__ float2 s_uw[ED];
    __shared__ float  s_su[C_];
    const int t = threadIdx.x;
    if (t < ED) s_uw[t] = make_float2(att[t], wgt[t]);
    __syncthreads();
    if (t < C_) {
        float ss = 0.f;
        #pragma unroll
        for (int m = 0; m < M_; ++m) { float v = s_uw[t * M_ + m].x; ss += v * v; }
        s_su[t] = 1.0f / fmaxf(sqrtf(ss), EPS);
    }
    __syncthreads();
    const int wave = t >> 6, lane = t & 63, g = lane >> 2, j = lane & 3;
    const int r = blockIdx.x * 64 + wave * 16 + g;
    if (r >= vocab) return;
    const float4* rowp = reinterpret_cast<const float4*>(emb + (long long)r * ED);
    float sq0 = 0.f, du0 = 0.f, dw0 = 0.f, sq1 = 0.f, du1 = 0.f, dw1 = 0.f;
    #pragma unroll
    for (int it = 0; it < 6; ++it) {
        const float4 v = rowp[4 * it + j];
        const float xs[4] = { v.x, v.y, v.z, v.w };
        #pragma unroll
        for (int k = 0; k < 4; ++k) {
            const int ebase = 16 * it + k;
            const float x = xs[k];
            const float2 uw = s_uw[ebase + 4 * j];
            if (ebase + 12 < M_)      { sq0 = fmaf(x,x,sq0); du0 = fmaf(x,uw.x,du0); dw0 = fmaf(x,uw.y,dw0); }
            else if (ebase >= M_)     { sq1 = fmaf(x,x,sq1); du1 = fmaf(x,uw.x,du1); dw1 = fmaf(x,uw.y,dw1); }
            else if (j == 0)          { sq0 = fmaf(x,x,sq0); du0 = fmaf(x,uw.x,du0); dw0 = fmaf(x,uw.y,dw0); }
            else                      { sq1 = fmaf(x,x,sq1); du1 = fmaf(x,uw.x,du1); dw1 = fmaf(x,uw.y,dw1); }
        }
    }
    if (j == 0) {
        const float4 v = rowp[24];
        const float xs[4] = { v.x, v.y, v.z, v.w };
        #pragma unroll
        for (int k = 0; k < 4; ++k) {
            const float2 uw = s_uw[96 + k];
            sq1 = fmaf(xs[k],xs[k],sq1); du1 = fmaf(xs[k],uw.x,du1); dw1 = fmaf(xs[k],uw.y,dw1);
        }
    }
    #pragma unroll
    for (int m = 1; m < 4; m <<= 1) {
        sq0 += __shfl_xor(sq0,m,4); du0 += __shfl_xor(du0,m,4); dw0 += __shfl_xor(dw0,m,4);
        sq1 += __shfl_xor(sq1,m,4); du1 += __shfl_xor(du1,m,4); dw1 += __shfl_xor(dw1,m,4);
    }
    if (j == 0) {
        const float cos0 = du0 / fmaxf(sqrtf(sq0), EPS) * s_su[0];
        const float cos1 = du1 / fmaxf(sqrtf(sq1), EPS) * s_su[1];
        const float a0 = __expf(cos0), a1 = __expf(cos1);
        reinterpret_cast<float4*>(tbl)[r] = make_float4(a0, a0 * dw0, a1, a1 * dw1);
    }
}

__global__ __launch_bounds__(256) void attend_kernel(
    const int* __restrict__ idx, const float4* __restrict__ tbl,
    float* __restrict__ out, int B, int L)
{
    const int wave = threadIdx.x >> 6, lane = threadIdx.x & 63;
    const int b = blockIdx.x * 4 + wave;
    if (b >= B) return;
    const int* ib = idx + (long long)b * L;
    float a0 = 0.f, a1 = 0.f, ap0 = 0.f, ap1 = 0.f;
    for (int l = lane; l < L; l += 64) {
        const float4 v = tbl[ib[l]];
        a0 += v.x; ap0 += v.y; a1 += v.z; ap1 += v.w;
    }
    #pragma unroll
    for (int off = 32; off > 0; off >>= 1) {
        a0 += __shfl_down(a0,off,64); a1 += __shfl_down(a1,off,64);
        ap0 += __shfl_down(ap0,off,64); ap1 += __shfl_down(ap1,off,64);
    }
    if (lane == 0) out[b] = ap0 / a0 + ap1 / a1;
}

extern "C" void kernel_launch(void* const* d_in, const int* in_sizes, int n_in,
                              void* d_out, int out_size, void* d_ws, size_t ws_size,
                              hipStream_t stream) {
    const int*   idx = (const int*)d_in[0];    // word_idxs [4096,200] int32
    const float* emb = (const float*)d_in[1];  // emb_table [100000,100] f32
    const float* wgt = (const float*)d_in[2];  // weights   [100,1] f32
    const float* att = (const float*)d_in[3];  // attend_u  [2,50] f32
    float* out = (float*)d_out;                // [4096] f32

    const int B     = out_size;                 // 4096
    const int L     = in_sizes[0] / B;          // 200
    const int vocab = in_sizes[1] / ED;         // 100000

    float* tbl = (float*)d_ws;                  // vocab * 16 B scratch
    const int nblk = (B + 3) / 4;               // 1024 for B=4096

    if (nblk <= 1024 && ws_size >= (size_t)vocab * 16 + 4096 + (size_t)(nblk + 1) * 8) {
        // slots after tbl, 256B-aligned
        const size_t slot_off = ((size_t)vocab * 16 + 255) & ~(size_t)255;
        unsigned long long* slots =
            (unsigned long long*)((char*)d_ws + slot_off);
        fused_kernel<<<nblk, 256, 0, stream>>>(idx, emb, wgt, att, out,
                                               tbl, slots, B, L, vocab, nblk);
    } else {
        row_stats_kernel<<<(vocab + 63) / 64, 256, 0, stream>>>(emb, wgt, att, tbl, vocab);
        attend_kernel<<<(B + 3) / 4, 256, 0, stream>>>(idx, (const float4*)tbl, out, B, L);
    }
}

// Round 6
// 93.058 us; speedup vs baseline: 3.4239x; 3.4239x over previous
//
#include <hip/hip_runtime.h>

// Problem constants (fixed by the reference):
//   B=4096, L=200, EMBEDDING_DIM=100, C=2 chunks of M=50, VOCAB=100000
constexpr int C_ = 2;
constexpr int M_ = 50;
constexpr int ED = 100;
constexpr float EPS = 1e-8f;

// tbl layout per row: (a0, a0*dw0, a1, a1*dw1)
//
// R4 lesson (measured): fusing the two passes with a software grid barrier
// (agent-scope acquire spin) costs ~240 us of idle spin on gfx950 -- the
// two-dispatch structure is strictly better. Dispatch overhead itself is
// only ~6-12 us; the 44 us workspace poison fill is harness-side and
// immovable. Remaining optimization budget is kernel latency-hiding.

// ---------------------------------------------------------------------------
// Pass 1: per-vocab-row statistics. FOUR LANES PER ROW, TWO ROWS PER QUAD.
//   Lane group {4g..4g+3} of a wave owns rows rA and rB = rA+16; lane j
//   reads float4 slots j, 4+j, ..., 20+j of each row, so the 4 lanes of a
//   group cover one full 64B line per load instruction (optimal line use),
//   and each thread has 12 independent global loads in flight (2x the MLP
//   of the one-row version) to hide HBM latency. Per-row accumulation
//   order is IDENTICAL to the harness-verified R2 kernel -> same numerics.
//   Grid: 782 blocks of 256 thr (128 rows/block) -- fully co-resident.
// ---------------------------------------------------------------------------
__global__ __launch_bounds__(256) void row_stats_kernel(
    const float* __restrict__ emb,   // [VOCAB, 100]
    const float* __restrict__ wgt,   // [100]
    const float* __restrict__ att,   // [100] = [2,50]
    float*       __restrict__ tbl,   // [VOCAB * 4]
    int vocab)
{
    __shared__ float2 s_uw[ED];   // (attend_u[e], weights[e])
    __shared__ float  s_su[C_];   // 1 / max(||u_c||, eps)

    const int t = threadIdx.x;
    if (t < ED) s_uw[t] = make_float2(att[t], wgt[t]);
    __syncthreads();
    if (t < C_) {
        float ss = 0.f;
        #pragma unroll
        for (int m = 0; m < M_; ++m) { float v = s_uw[t * M_ + m].x; ss += v * v; }
        s_su[t] = 1.0f / fmaxf(sqrtf(ss), EPS);
    }
    __syncthreads();

    const int wave = t >> 6;
    const int lane = t & 63;
    const int g    = lane >> 2;               // row-in-wave (0..15)
    const int j    = lane & 3;                // float4 slot within group
    const int rA   = blockIdx.x * 128 + wave * 32 + g;   // first row
    const int rB   = rA + 16;                            // second row
    const bool okA = (rA < vocab);
    const bool okB = (rB < vocab);
    if (!okA) return;                          // rows ascend; !okA => !okB

    const float4* rpA = reinterpret_cast<const float4*>(emb + (long long)rA * ED);
    const float4* rpB = reinterpret_cast<const float4*>(emb + (long long)rB * ED);

    // Issue all main loads up front (independent -> 12 outstanding per thread)
    float4 va[6], vb[6];
    #pragma unroll
    for (int it = 0; it < 6; ++it) va[it] = rpA[4 * it + j];
    if (okB) {
        #pragma unroll
        for (int it = 0; it < 6; ++it) vb[it] = rpB[4 * it + j];
    }
    float4 ta, tb;
    if (j == 0) {
        ta = rpA[24];
        if (okB) tb = rpB[24];
    }

    float AsQ0 = 0.f, AdU0 = 0.f, AdW0 = 0.f, AsQ1 = 0.f, AdU1 = 0.f, AdW1 = 0.f;
    float BsQ0 = 0.f, BdU0 = 0.f, BdW0 = 0.f, BsQ1 = 0.f, BdU1 = 0.f, BdW1 = 0.f;

    #pragma unroll
    for (int it = 0; it < 6; ++it) {
        const float xsA[4] = { va[it].x, va[it].y, va[it].z, va[it].w };
        const float xsB[4] = { vb[it].x, vb[it].y, vb[it].z, vb[it].w };
        #pragma unroll
        for (int k = 0; k < 4; ++k) {
            const int ebase = 16 * it + k;    // element e = ebase + 4*j
            const float2 uw = s_uw[ebase + 4 * j];
            const float xA = xsA[k];
            const float xB = xsB[k];
            if (ebase + 12 < M_) {            // chunk 0 for every j
                AsQ0 = fmaf(xA, xA, AsQ0); AdU0 = fmaf(xA, uw.x, AdU0); AdW0 = fmaf(xA, uw.y, AdW0);
                BsQ0 = fmaf(xB, xB, BsQ0); BdU0 = fmaf(xB, uw.x, BdU0); BdW0 = fmaf(xB, uw.y, BdW0);
            } else if (ebase >= M_) {         // chunk 1 for every j
                AsQ1 = fmaf(xA, xA, AsQ1); AdU1 = fmaf(xA, uw.x, AdU1); AdW1 = fmaf(xA, uw.y, AdW1);
                BsQ1 = fmaf(xB, xB, BsQ1); BdU1 = fmaf(xB, uw.x, BdU1); BdW1 = fmaf(xB, uw.y, BdW1);
            } else {                          // straddle: j==0 chunk0, else chunk1
                if (j == 0) {
                    AsQ0 = fmaf(xA, xA, AsQ0); AdU0 = fmaf(xA, uw.x, AdU0); AdW0 = fmaf(xA, uw.y, AdW0);
                    BsQ0 = fmaf(xB, xB, BsQ0); BdU0 = fmaf(xB, uw.x, BdU0); BdW0 = fmaf(xB, uw.y, BdW0);
                } else {
                    AsQ1 = fmaf(xA, xA, AsQ1); AdU1 = fmaf(xA, uw.x, AdU1); AdW1 = fmaf(xA, uw.y, AdW1);
                    BsQ1 = fmaf(xB, xB, BsQ1); BdU1 = fmaf(xB, uw.x, BdU1); BdW1 = fmaf(xB, uw.y, BdW1);
                }
            }
        }
    }
    if (j == 0) {                             // tail float4 #24: elements 96..99
        const float xsA[4] = { ta.x, ta.y, ta.z, ta.w };
        const float xsB[4] = { tb.x, tb.y, tb.z, tb.w };
        #pragma unroll
        for (int k = 0; k < 4; ++k) {
            const float2 uw = s_uw[96 + k];
            AsQ1 = fmaf(xsA[k], xsA[k], AsQ1); AdU1 = fmaf(xsA[k], uw.x, AdU1); AdW1 = fmaf(xsA[k], uw.y, AdW1);
            BsQ1 = fmaf(xsB[k], xsB[k], BsQ1); BdU1 = fmaf(xsB[k], uw.x, BdU1); BdW1 = fmaf(xsB[k], uw.y, BdW1);
        }
    }

    // quad tree-reduce all 12 partials (whole quad active)
    #pragma unroll
    for (int m = 1; m < 4; m <<= 1) {
        AsQ0 += __shfl_xor(AsQ0, m, 4); AdU0 += __shfl_xor(AdU0, m, 4); AdW0 += __shfl_xor(AdW0, m, 4);
        AsQ1 += __shfl_xor(AsQ1, m, 4); AdU1 += __shfl_xor(AdU1, m, 4); AdW1 += __shfl_xor(AdW1, m, 4);
        BsQ0 += __shfl_xor(BsQ0, m, 4); BdU0 += __shfl_xor(BdU0, m, 4); BdW0 += __shfl_xor(BdW0, m, 4);
        BsQ1 += __shfl_xor(BsQ1, m, 4); BdU1 += __shfl_xor(BdU1, m, 4); BdW1 += __shfl_xor(BdW1, m, 4);
    }

    if (j == 0) {
        {
            const float cos0 = AdU0 / fmaxf(sqrtf(AsQ0), EPS) * s_su[0];
            const float cos1 = AdU1 / fmaxf(sqrtf(AsQ1), EPS) * s_su[1];
            const float a0 = __expf(cos0);
            const float a1 = __expf(cos1);
            reinterpret_cast<float4*>(tbl)[rA] = make_float4(a0, a0 * AdW0, a1, a1 * AdW1);
        }
        if (okB) {
            const float cos0 = BdU0 / fmaxf(sqrtf(BsQ0), EPS) * s_su[0];
            const float cos1 = BdU1 / fmaxf(sqrtf(BsQ1), EPS) * s_su[1];
            const float a0 = __expf(cos0);
            const float a1 = __expf(cos1);
            reinterpret_cast<float4*>(tbl)[rB] = make_float4(a0, a0 * BdW0, a1, a1 * BdW1);
        }
    }
}

// ---------------------------------------------------------------------------
// Pass 2: one WAVE per batch element (harness-verified R0 shape). Each thread
// has up to 4 independent idx-load+gather pairs in flight; pure wave-shuffle
// reduce, no LDS, no __syncthreads. 1024 blocks -> 4 blocks/CU, 16 waves/CU,
// same per-CU outstanding-gather count as the 2-wave variant but without the
// block-level sync serialization.
// ---------------------------------------------------------------------------
__global__ __launch_bounds__(256) void attend_kernel(
    const int*    __restrict__ idx,  // [B, L]
    const float4* __restrict__ tbl,  // [VOCAB] as (a0, ap0, a1, ap1)
    float*        __restrict__ out,  // [B]
    int B, int L)
{
    const int wave = threadIdx.x >> 6;
    const int lane = threadIdx.x & 63;
    const int b    = blockIdx.x * 4 + wave;
    if (b >= B) return;

    const int* ib = idx + (long long)b * L;
    float a0 = 0.f, a1 = 0.f, ap0 = 0.f, ap1 = 0.f;
    #pragma unroll 4
    for (int l = lane; l < L; l += 64) {       // coalesced idx read, cached gather
        const float4 v = tbl[ib[l]];
        a0 += v.x; ap0 += v.y; a1 += v.z; ap1 += v.w;
    }

    #pragma unroll
    for (int off = 32; off > 0; off >>= 1) {
        a0  += __shfl_down(a0,  off, 64);
        a1  += __shfl_down(a1,  off, 64);
        ap0 += __shfl_down(ap0, off, 64);
        ap1 += __shfl_down(ap1, off, 64);
    }
    if (lane == 0) out[b] = ap0 / a0 + ap1 / a1;
}

extern "C" void kernel_launch(void* const* d_in, const int* in_sizes, int n_in,
                              void* d_out, int out_size, void* d_ws, size_t ws_size,
                              hipStream_t stream) {
    const int*   idx = (const int*)d_in[0];    // word_idxs [4096,200] int32
    const float* emb = (const float*)d_in[1];  // emb_table [100000,100] f32
    const float* wgt = (const float*)d_in[2];  // weights   [100,1] f32
    const float* att = (const float*)d_in[3];  // attend_u  [2,50] f32
    float* out = (float*)d_out;                // [4096] f32

    const int B     = out_size;                 // 4096
    const int L     = in_sizes[0] / B;          // 200
    const int vocab = in_sizes[1] / ED;         // 100000

    float* tbl = (float*)d_ws;                  // 100000 * 16 B = 1.6 MB scratch

    row_stats_kernel<<<(vocab + 127) / 128, 256, 0, stream>>>(emb, wgt, att, tbl, vocab);
    attend_kernel<<<(B + 3) / 4, 256, 0, stream>>>(idx, (const float4*)tbl, out, B, L);
}